// Round 7
// baseline (1492.283 us; speedup 1.0000x reference)
//
#include <hip/hip_runtime.h>

#define NI 4096
#define NH 8192
#define NO 2048
#define NBLK 2048
#define NWAVE (NBLK * 4)   // 8192 waves = 32 waves/CU on 256 CUs (max occupancy)

typedef float f4 __attribute__((ext_vector_type(4)));

__device__ __forceinline__ float apply_act(float x, int id) {
    switch (id) {
        case 0:  return x;
        case 1:  return x >= 0.f ? x : 0.01f * x;   // leaky_relu
        case 2:  return fmaxf(x, 0.f);              // relu
        case 3:  return 1.f / (1.f + expf(-x));     // sigmoid
        default: return tanhf(x);                   // tanh
    }
}

// One 64-lane wave: dot(Wrow, x), float4 loads, butterfly reduce (R2 shape).
template <bool NT>
__device__ __forceinline__ float wave_dot(const float* __restrict__ Wrow,
                                          const float* __restrict__ x,
                                          int K, int lane) {
    const f4* __restrict__ W4 = (const f4*)Wrow;
    const f4* __restrict__ x4 = (const f4*)x;
    float acc = 0.f;
    const int n4 = K >> 2;
    #pragma unroll 4
    for (int i = lane; i < n4; i += 64) {
        f4 w = NT ? __builtin_nontemporal_load(W4 + i) : W4[i];
        f4 v = x4[i];
        acc = fmaf(w.x, v.x, acc);
        acc = fmaf(w.y, v.y, acc);
        acc = fmaf(w.z, v.z, acc);
        acc = fmaf(w.w, v.w, acc);
    }
    #pragma unroll
    for (int off = 32; off; off >>= 1) acc += __shfl_xor(acc, off, 64);
    return acc;
}

// Grid-wide barrier: agent-scope arrive counter + release/acquire flag.
// cnt/flag zeroed by hipMemsetAsync before each launch (replay-safe).
__device__ __forceinline__ void grid_barrier(int* cnt, int* flag) {
    __syncthreads();
    if (threadIdx.x == 0) {
        int old = __hip_atomic_fetch_add(cnt, 1, __ATOMIC_ACQ_REL,
                                         __HIP_MEMORY_SCOPE_AGENT);
        if (old == NBLK - 1) {
            __hip_atomic_store(flag, 1, __ATOMIC_RELEASE,
                               __HIP_MEMORY_SCOPE_AGENT);
        } else {
            while (!__hip_atomic_load(flag, __ATOMIC_ACQUIRE,
                                      __HIP_MEMORY_SCOPE_AGENT))
                __builtin_amdgcn_s_sleep(1);
        }
    }
    __syncthreads();
}

__global__ __launch_bounds__(256, 8) void k_fused(
        const float* __restrict__ xin,
        const float* __restrict__ W_i2h,
        const float* __restrict__ W_h2h,
        const float* __restrict__ W_o2h,
        const float* __restrict__ W_i2o,
        const float* __restrict__ W_h2o,
        const float* __restrict__ W_o2o,
        const float* __restrict__ h_resp,
        const float* __restrict__ h_bias,
        const float* __restrict__ o_resp,
        const float* __restrict__ o_bias,
        const float* __restrict__ a0,
        const float* __restrict__ o0,
        const int* __restrict__ h_ids,
        const int* __restrict__ o_ids,
        float* __restrict__ c_h,
        float* __restrict__ act_a,
        float* __restrict__ act_b,
        float* __restrict__ act_c,
        int* __restrict__ flags,
        int* __restrict__ bar,
        float* __restrict__ out) {
    const int wave = threadIdx.x >> 6;
    const int lane = threadIdx.x & 63;
    const int gw = blockIdx.x * 4 + wave;   // 0 .. NWAVE-1 == row index

    // ---- phase 0: zero-vector flags ----
    {
        int gtid = blockIdx.x * 256 + threadIdx.x;
        int f0 = 0, f1 = 0, f2 = 0;
        if (gtid < NI) f0 = (xin[gtid] != 0.f);
        if (gtid < NH) f1 = (a0[gtid]  != 0.f);
        if (gtid < NO) f2 = (o0[gtid]  != 0.f);
        if (__any(f0) && lane == 0) atomicOr(flags + 0, 1);
        if (__any(f1) && lane == 0) atomicOr(flags + 1, 1);
        if (__any(f2) && lane == 0) atomicOr(flags + 2, 1);
    }
    grid_barrier(bar + 0, bar + 4);
    const int f0 = flags[0], f1 = flags[1], f2 = flags[2];

    // ---- phase 1: c_h (loop-invariant) + step-1 epilogue (1 row/wave) ----
    {
        int m = gw;
        float c = 0.f;
        if (f0) c += wave_dot<true>(W_i2h + (size_t)m * NI, xin, NI, lane);
        if (f2) c += wave_dot<true>(W_o2h + (size_t)m * NO, o0,  NO, lane);
        float d = 0.f;
        if (f1) d = wave_dot<false>(W_h2h + (size_t)m * NH, a0, NH, lane);
        if (lane == 0) {
            c_h[m] = c;
            act_a[m] = apply_act(fmaf(h_resp[m], c + d, h_bias[m]), h_ids[m]);
        }
    }
    grid_barrier(bar + 1, bar + 5);

    // ---- phase 2: step 2 (normal loads: allocate W_h2h into L3) ----
    {
        int m = gw;
        float d = wave_dot<false>(W_h2h + (size_t)m * NH, act_a, NH, lane);
        if (lane == 0)
            act_b[m] = apply_act(fmaf(h_resp[m], c_h[m] + d, h_bias[m]), h_ids[m]);
    }
    grid_barrier(bar + 2, bar + 6);

    // ---- phase 3: step 3 (re-read W_h2h: intra-kernel L3 hits) ----
    {
        int m = gw;
        float d = wave_dot<false>(W_h2h + (size_t)m * NH, act_b, NH, lane);
        if (lane == 0)
            act_c[m] = apply_act(fmaf(h_resp[m], c_h[m] + d, h_bias[m]), h_ids[m]);
    }
    grid_barrier(bar + 3, bar + 7);

    // ---- phase 4: output layer, 1 row per block, 4-wave split-K ----
    {
        __shared__ float part[4];
        int m = blockIdx.x;          // NBLK == NO
        float acc = wave_dot<true>(W_h2o + (size_t)m * NH + wave * (NH / 4),
                                   act_c + wave * (NH / 4), NH / 4, lane);
        if (wave < 2 && f0)
            acc += wave_dot<true>(W_i2o + (size_t)m * NI + wave * (NI / 2),
                                  xin + wave * (NI / 2), NI / 2, lane);
        if (wave == 2 && f2)
            acc += wave_dot<true>(W_o2o + (size_t)m * NO, o0, NO, lane);
        if (lane == 0) part[wave] = acc;
        __syncthreads();
        if (threadIdx.x == 0) {
            float dot = part[0] + part[1] + part[2] + part[3];
            out[m] = apply_act(fmaf(o_resp[m], dot, o_bias[m]), o_ids[m]);
        }
    }
}

extern "C" void kernel_launch(void* const* d_in, const int* in_sizes, int n_in,
                              void* d_out, int out_size, void* d_ws, size_t ws_size,
                              hipStream_t stream) {
    const float* inputs   = (const float*)d_in[0];
    const float* W_i2h    = (const float*)d_in[1];
    const float* W_h2h    = (const float*)d_in[2];
    const float* W_o2h    = (const float*)d_in[3];
    const float* W_i2o    = (const float*)d_in[4];
    const float* W_h2o    = (const float*)d_in[5];
    const float* W_o2o    = (const float*)d_in[6];
    const float* h_resp   = (const float*)d_in[7];
    const float* h_bias   = (const float*)d_in[8];
    const float* o_resp   = (const float*)d_in[9];
    const float* o_bias   = (const float*)d_in[10];
    const float* activs0  = (const float*)d_in[11];
    const float* outputs0 = (const float*)d_in[12];
    const int*   h_ids    = (const int*)d_in[13];
    const int*   o_ids    = (const int*)d_in[14];

    float* ws    = (float*)d_ws;
    float* c_h   = ws;            // NH
    float* act_a = ws + NH;       // NH
    float* act_b = ws + 2 * NH;   // NH
    float* act_c = ws + 3 * NH;   // NH
    int*   ints  = (int*)(ws + 4 * NH);
    int*   flags = ints;          // 3
    int*   bar   = ints + 3;      // 8 (4 cnt + 4 flag)

    // zero flags + barrier state every call (graph replays re-run this)
    hipMemsetAsync(ints, 0, 11 * sizeof(int), stream);

    k_fused<<<NBLK, 256, 0, stream>>>(inputs, W_i2h, W_h2h, W_o2h, W_i2o, W_h2o,
                                      W_o2o, h_resp, h_bias, o_resp, o_bias,
                                      activs0, outputs0, h_ids, o_ids,
                                      c_h, act_a, act_b, act_c, flags, bar,
                                      (float*)d_out);
}

// Round 8
// 721.530 us; speedup vs baseline: 2.0682x; 2.0682x over previous
//
#include <hip/hip_runtime.h>

#define NI 4096
#define NH 8192
#define NO 2048
#define NBLK 2048   // exactly 8 blocks/CU * 256 CUs -> all co-resident, 32 waves/CU

typedef float f4 __attribute__((ext_vector_type(4)));

__device__ __forceinline__ float apply_act(float x, int id) {
    switch (id) {
        case 0:  return x;
        case 1:  return x >= 0.f ? x : 0.01f * x;   // leaky_relu
        case 2:  return fmaxf(x, 0.f);              // relu
        case 3:  return 1.f / (1.f + expf(-x));     // sigmoid
        default: return tanhf(x);                   // tanh
    }
}

// One 64-lane wave: dot(Wrow, x), float4 loads, butterfly reduce (R2 shape).
template <bool NT>
__device__ __forceinline__ float wave_dot(const float* __restrict__ Wrow,
                                          const float* __restrict__ x,
                                          int K, int lane) {
    const f4* __restrict__ W4 = (const f4*)Wrow;
    const f4* __restrict__ x4 = (const f4*)x;
    float acc = 0.f;
    const int n4 = K >> 2;
    #pragma unroll 4
    for (int i = lane; i < n4; i += 64) {
        f4 w = NT ? __builtin_nontemporal_load(W4 + i) : W4[i];
        f4 v = x4[i];
        acc = fmaf(w.x, v.x, acc);
        acc = fmaf(w.y, v.y, acc);
        acc = fmaf(w.z, v.z, acc);
        acc = fmaf(w.w, v.w, acc);
    }
    #pragma unroll
    for (int off = 32; off; off >>= 1) acc += __shfl_xor(acc, off, 64);
    return acc;
}

// Grid barrier: RELAXED poll (no per-iteration cache invalidate!) + one
// acquire fence on exit. cnt/flag zeroed by hipMemsetAsync each call.
__device__ __forceinline__ void grid_barrier(int* cnt, int* flag) {
    __syncthreads();
    if (threadIdx.x == 0) {
        int old = __hip_atomic_fetch_add(cnt, 1, __ATOMIC_ACQ_REL,
                                         __HIP_MEMORY_SCOPE_AGENT);
        if (old == NBLK - 1) {
            __hip_atomic_store(flag, 1, __ATOMIC_RELEASE,
                               __HIP_MEMORY_SCOPE_AGENT);
        } else {
            while (__hip_atomic_load(flag, __ATOMIC_RELAXED,
                                     __HIP_MEMORY_SCOPE_AGENT) == 0)
                __builtin_amdgcn_s_sleep(8);
            __builtin_amdgcn_fence(__ATOMIC_ACQUIRE, "agent");
        }
    }
    __syncthreads();
}

__global__ __launch_bounds__(256, 8) void k_fused(
        const float* __restrict__ xin,
        const float* __restrict__ W_i2h,
        const float* __restrict__ W_h2h,
        const float* __restrict__ W_o2h,
        const float* __restrict__ W_i2o,
        const float* __restrict__ W_h2o,
        const float* __restrict__ W_o2o,
        const float* __restrict__ h_resp,
        const float* __restrict__ h_bias,
        const float* __restrict__ o_resp,
        const float* __restrict__ o_bias,
        const float* __restrict__ a0,
        const float* __restrict__ o0,
        const int* __restrict__ h_ids,
        const int* __restrict__ o_ids,
        float* __restrict__ c_h,
        float* __restrict__ act_a,
        float* __restrict__ act_b,
        float* __restrict__ act_c,
        int* __restrict__ flags,   // [0]=f1(a0), [1]=f2(o0)
        int* __restrict__ ready,
        int* __restrict__ bar,     // 3 cnt + 3 flag
        float* __restrict__ out) {
    const int wave = threadIdx.x >> 6;
    const int lane = threadIdx.x & 63;
    const int gw = blockIdx.x * 4 + wave;   // 0 .. 8191 == hidden row

    // ---- block 0 only: scan a0/o0 for zero-ness, publish flags ----
    if (blockIdx.x == 0) {
        __shared__ int s1, s2;
        int t = threadIdx.x;
        if (t == 0) { s1 = 0; s2 = 0; }
        __syncthreads();
        int f1 = 0, f2 = 0;
        for (int i = t; i < NH; i += 256) f1 |= (a0[i] != 0.f);
        for (int i = t; i < NO; i += 256) f2 |= (o0[i] != 0.f);
        if (__any(f1) && lane == 0) atomicOr(&s1, 1);
        if (__any(f2) && lane == 0) atomicOr(&s2, 1);
        __syncthreads();
        if (t == 0) {
            flags[0] = s1; flags[1] = s2;
            __hip_atomic_store(ready, 1, __ATOMIC_RELEASE,
                               __HIP_MEMORY_SCOPE_AGENT);
        }
    }

    // ---- phase 1: unconditional i2h dot (overlaps block-0's flag scan) ----
    float c = wave_dot<true>(W_i2h + (size_t)gw * NI, xin, NI, lane);

    // flags ready? (poll relaxed, acquire once; scan finished ~20us ago)
    if (threadIdx.x == 0) {
        while (__hip_atomic_load(ready, __ATOMIC_RELAXED,
                                 __HIP_MEMORY_SCOPE_AGENT) == 0)
            __builtin_amdgcn_s_sleep(8);
        __builtin_amdgcn_fence(__ATOMIC_ACQUIRE, "agent");
    }
    __syncthreads();
    const int f1 = flags[0], f2 = flags[1];

    // conditional loop-invariant o2h part + conditional step-1 h2h part
    {
        if (f2) c += wave_dot<true>(W_o2h + (size_t)gw * NO, o0, NO, lane);
        float d = 0.f;
        if (f1) d = wave_dot<false>(W_h2h + (size_t)gw * NH, a0, NH, lane);
        if (lane == 0) {
            c_h[gw] = c;
            act_a[gw] = apply_act(fmaf(h_resp[gw], c + d, h_bias[gw]), h_ids[gw]);
        }
    }
    grid_barrier(bar + 0, bar + 3);

    // ---- phase 2: step 2 (normal loads: allocate W_h2h into L2/L3) ----
    {
        float d = wave_dot<false>(W_h2h + (size_t)gw * NH, act_a, NH, lane);
        if (lane == 0)
            act_b[gw] = apply_act(fmaf(h_resp[gw], c_h[gw] + d, h_bias[gw]),
                                  h_ids[gw]);
    }
    grid_barrier(bar + 1, bar + 4);

    // ---- phase 3: step 3 (re-read W_h2h: intra-kernel L3 hits) ----
    {
        float d = wave_dot<false>(W_h2h + (size_t)gw * NH, act_b, NH, lane);
        if (lane == 0)
            act_c[gw] = apply_act(fmaf(h_resp[gw], c_h[gw] + d, h_bias[gw]),
                                  h_ids[gw]);
    }
    grid_barrier(bar + 2, bar + 5);

    // ---- phase 4: output layer, 1 row per block, 4-wave split-K ----
    {
        __shared__ float part[4];
        int m = blockIdx.x;          // NBLK == NO
        float acc = wave_dot<true>(W_h2o + (size_t)m * NH + wave * (NH / 4),
                                   act_c + wave * (NH / 4), NH / 4, lane);
        if (wave < 2)
            acc += wave_dot<true>(W_i2o + (size_t)m * NI + wave * (NI / 2),
                                  xin + wave * (NI / 2), NI / 2, lane);
        if (wave == 2 && f2)
            acc += wave_dot<true>(W_o2o + (size_t)m * NO, o0, NO, lane);
        if (lane == 0) part[wave] = acc;
        __syncthreads();
        if (threadIdx.x == 0) {
            float dot = part[0] + part[1] + part[2] + part[3];
            out[m] = apply_act(fmaf(o_resp[m], dot, o_bias[m]), o_ids[m]);
        }
    }
}

extern "C" void kernel_launch(void* const* d_in, const int* in_sizes, int n_in,
                              void* d_out, int out_size, void* d_ws, size_t ws_size,
                              hipStream_t stream) {
    const float* inputs   = (const float*)d_in[0];
    const float* W_i2h    = (const float*)d_in[1];
    const float* W_h2h    = (const float*)d_in[2];
    const float* W_o2h    = (const float*)d_in[3];
    const float* W_i2o    = (const float*)d_in[4];
    const float* W_h2o    = (const float*)d_in[5];
    const float* W_o2o    = (const float*)d_in[6];
    const float* h_resp   = (const float*)d_in[7];
    const float* h_bias   = (const float*)d_in[8];
    const float* o_resp   = (const float*)d_in[9];
    const float* o_bias   = (const float*)d_in[10];
    const float* activs0  = (const float*)d_in[11];
    const float* outputs0 = (const float*)d_in[12];
    const int*   h_ids    = (const int*)d_in[13];
    const int*   o_ids    = (const int*)d_in[14];

    float* ws    = (float*)d_ws;
    float* c_h   = ws;            // NH
    float* act_a = ws + NH;       // NH
    float* act_b = ws + 2 * NH;   // NH
    float* act_c = ws + 3 * NH;   // NH
    int*   ints  = (int*)(ws + 4 * NH);
    int*   flags = ints;          // 2
    int*   ready = ints + 2;      // 1
    int*   bar   = ints + 3;      // 6 (3 cnt + 3 flag)

    // zero flags/ready/barrier state every call (replay-safe)
    hipMemsetAsync(ints, 0, 9 * sizeof(int), stream);

    k_fused<<<NBLK, 256, 0, stream>>>(inputs, W_i2h, W_h2h, W_o2h, W_i2o, W_h2o,
                                      W_o2o, h_resp, h_bias, o_resp, o_bias,
                                      activs0, outputs0, h_ids, o_ids,
                                      c_h, act_a, act_b, act_c, flags, ready, bar,
                                      (float*)d_out);
}

// Round 9
// 127.034 us; speedup vs baseline: 11.7471x; 5.6798x over previous
//
#include <hip/hip_runtime.h>

#define NI 4096
#define NH 8192
#define NO 2048

typedef float f4 __attribute__((ext_vector_type(4)));

__device__ __forceinline__ float apply_act(float x, int id) {
    switch (id) {
        case 0:  return x;
        case 1:  return x >= 0.f ? x : 0.01f * x;   // leaky_relu
        case 2:  return fmaxf(x, 0.f);              // relu
        case 3:  return 1.f / (1.f + expf(-x));     // sigmoid
        default: return tanhf(x);                   // tanh
    }
}

// One 64-lane wave: dot(Wrow, x), float4 loads, butterfly reduce (R2 shape,
// unroll 4 — proven 134 µs config; VGPR stays ~32 -> 8 waves/SIMD).
template <bool NT>
__device__ __forceinline__ float wave_dot(const float* __restrict__ Wrow,
                                          const float* __restrict__ x,
                                          int K, int lane) {
    const f4* __restrict__ W4 = (const f4*)Wrow;
    const f4* __restrict__ x4 = (const f4*)x;
    float acc = 0.f;
    const int n4 = K >> 2;
    #pragma unroll 4
    for (int i = lane; i < n4; i += 64) {
        f4 w = NT ? __builtin_nontemporal_load(W4 + i) : W4[i];
        f4 v = x4[i];
        acc = fmaf(w.x, v.x, acc);
        acc = fmaf(w.y, v.y, acc);
        acc = fmaf(w.z, v.z, acc);
        acc = fmaf(w.w, v.w, acc);
    }
    #pragma unroll
    for (int off = 32; off; off >>= 1) acc += __shfl_xor(acc, off, 64);
    return acc;
}

// In-block "any nonzero" scan of a float vector (f4 loads), all threads get
// the result. Vector is tiny (8-32 KB) -> L2-broadcast after first touch.
__device__ __forceinline__ int block_any_nonzero(const float* __restrict__ v,
                                                 int n, int* sflag, int lane) {
    if (threadIdx.x == 0) *sflag = 0;
    __syncthreads();
    const f4* v4 = (const f4*)v;
    int f = 0;
    for (int i = threadIdx.x; i < (n >> 2); i += 256) {
        f4 w = v4[i];
        f |= (w.x != 0.f) | (w.y != 0.f) | (w.z != 0.f) | (w.w != 0.f);
    }
    if (__any(f) && lane == 0) atomicOr(sflag, 1);
    __syncthreads();
    return *sflag;
}

// Fused: per-block flag scan + c_h (loop-invariant) + step-1 epilogue.
// i2h dot is unconditional (zero xin would just produce a zero dot).
__global__ __launch_bounds__(256) void k_h_init(const float* __restrict__ W_i2h,
                                                const float* __restrict__ W_o2h,
                                                const float* __restrict__ W_h2h,
                                                const float* __restrict__ xin,
                                                const float* __restrict__ o0,
                                                const float* __restrict__ a0,
                                                const float* __restrict__ resp,
                                                const float* __restrict__ bias,
                                                const int* __restrict__ ids,
                                                float* __restrict__ c_h,
                                                float* __restrict__ act_a) {
    __shared__ int s1, s2;
    int wave = threadIdx.x >> 6;
    int lane = threadIdx.x & 63;
    int F1 = block_any_nonzero(a0, NH, &s1, lane);   // activs0 nonzero?
    int F2 = block_any_nonzero(o0, NO, &s2, lane);   // outputs0 nonzero?
    int m = blockIdx.x * 4 + wave;
    float c = wave_dot<true>(W_i2h + (size_t)m * NI, xin, NI, lane);
    if (F2) c += wave_dot<true>(W_o2h + (size_t)m * NO, o0, NO, lane);
    float d = 0.f;
    if (F1) d = wave_dot<false>(W_h2h + (size_t)m * NH, a0, NH, lane);
    if (lane == 0) {
        c_h[m] = c;
        act_a[m] = apply_act(fmaf(resp[m], c + d, bias[m]), ids[m]);
    }
}

// Hidden step (R2-identical): 1 row/wave, normal cached h2h loads.
__global__ __launch_bounds__(256) void k_step(const float* __restrict__ W_h2h,
                                              const float* __restrict__ x,
                                              const float* __restrict__ c_h,
                                              const float* __restrict__ resp,
                                              const float* __restrict__ bias,
                                              const int* __restrict__ ids,
                                              float* __restrict__ out) {
    int wave = threadIdx.x >> 6;
    int lane = threadIdx.x & 63;
    int m = blockIdx.x * 4 + wave;
    float dot = wave_dot<false>(W_h2h + (size_t)m * NH, x, NH, lane);
    if (lane == 0) {
        float pre = fmaf(resp[m], c_h[m] + dot, bias[m]);
        out[m] = apply_act(pre, ids[m]);
    }
}

// Output layer: 1 row per block, 4-wave split-K (32 waves/CU), LDS combine.
// i2o unconditional; o2o gated by per-block o0 scan.
__global__ __launch_bounds__(256) void k_final(const float* __restrict__ W_i2o,
                                               const float* __restrict__ W_o2o,
                                               const float* __restrict__ W_h2o,
                                               const float* __restrict__ xin,
                                               const float* __restrict__ o0,
                                               const float* __restrict__ act,
                                               const float* __restrict__ resp,
                                               const float* __restrict__ bias,
                                               const int* __restrict__ ids,
                                               float* __restrict__ out) {
    __shared__ float part[4];
    __shared__ int s2;
    int wave = threadIdx.x >> 6;
    int lane = threadIdx.x & 63;
    int F2 = block_any_nonzero(o0, NO, &s2, lane);
    int m = blockIdx.x;                       // gridDim.x == NO
    float acc = wave_dot<true>(W_h2o + (size_t)m * NH + wave * (NH / 4),
                               act + wave * (NH / 4), NH / 4, lane);
    if (wave < 2)
        acc += wave_dot<true>(W_i2o + (size_t)m * NI + wave * (NI / 2),
                              xin + wave * (NI / 2), NI / 2, lane);
    if (wave == 3 && F2)
        acc += wave_dot<true>(W_o2o + (size_t)m * NO, o0, NO, lane);
    if (lane == 0) part[wave] = acc;
    __syncthreads();
    if (threadIdx.x == 0) {
        float dot = part[0] + part[1] + part[2] + part[3];
        out[m] = apply_act(fmaf(resp[m], dot, bias[m]), ids[m]);
    }
}

extern "C" void kernel_launch(void* const* d_in, const int* in_sizes, int n_in,
                              void* d_out, int out_size, void* d_ws, size_t ws_size,
                              hipStream_t stream) {
    const float* inputs   = (const float*)d_in[0];
    const float* W_i2h    = (const float*)d_in[1];
    const float* W_h2h    = (const float*)d_in[2];
    const float* W_o2h    = (const float*)d_in[3];
    const float* W_i2o    = (const float*)d_in[4];
    const float* W_h2o    = (const float*)d_in[5];
    const float* W_o2o    = (const float*)d_in[6];
    const float* h_resp   = (const float*)d_in[7];
    const float* h_bias   = (const float*)d_in[8];
    const float* o_resp   = (const float*)d_in[9];
    const float* o_bias   = (const float*)d_in[10];
    const float* activs0  = (const float*)d_in[11];
    const float* outputs0 = (const float*)d_in[12];
    const int*   h_ids    = (const int*)d_in[13];
    const int*   o_ids    = (const int*)d_in[14];

    float* ws    = (float*)d_ws;
    float* c_h   = ws;            // NH
    float* act_a = ws + NH;       // NH
    float* act_b = ws + 2 * NH;   // NH
    float* act_c = ws + 3 * NH;   // NH

    // c_h + step 1 (flags computed in-block; no separate dispatch, no memset)
    k_h_init<<<NH / 4, 256, 0, stream>>>(W_i2h, W_o2h, W_h2h, inputs, outputs0,
                                         activs0, h_resp, h_bias, h_ids,
                                         c_h, act_a);
    // step 2
    k_step<<<NH / 4, 256, 0, stream>>>(W_h2h, act_a, c_h, h_resp, h_bias, h_ids,
                                       act_b);
    // step 3
    k_step<<<NH / 4, 256, 0, stream>>>(W_h2h, act_b, c_h, h_resp, h_bias, h_ids,
                                       act_c);
    // output layer (split-K, full occupancy)
    k_final<<<NO, 256, 0, stream>>>(W_i2o, W_o2o, W_h2o, inputs, outputs0, act_c,
                                    o_resp, o_bias, o_ids, (float*)d_out);
}